// Round 6
// baseline (487.027 us; speedup 1.0000x reference)
//
#include <hip/hip_runtime.h>
#include <hip/hip_fp16.h>
#include <math.h>

#define NN 50000
#define NR 2000
#define NT 1000000
#define HID 128
#define OSTRIDE 768
#define CH 256  // halves per compact feature row (e:0..127, r:128..255)

typedef float f32x4 __attribute__((ext_vector_type(4)));
typedef unsigned u32x4 __attribute__((ext_vector_type(4)));
typedef unsigned u32x2 __attribute__((ext_vector_type(2)));

__device__ __forceinline__ float wsum64(float v) {
#pragma unroll
  for (int off = 32; off > 0; off >>= 1) v += __shfl_xor(v, off, 64);
  return v;
}
__device__ __forceinline__ unsigned pack2(float x, float y) {
  __half2 h = __floats2half2_rn(x, y);
  union { __half2 h; unsigned u; } c; c.h = h; return c.u;
}
__device__ __forceinline__ float2 unpack2(unsigned u) {
  union { unsigned u; __half2 h; } c; c.u = u;
  return __half22float2(c.h);
}
__device__ __forceinline__ void nt_store4(const float4& v, float* p) {
  f32x4 t = {v.x, v.y, v.z, v.w};
  __builtin_nontemporal_store(t, (f32x4*)p);
}

// ---------- row pointers for all three sorted covering adjacencies ----------
__global__ void rowptr3_kernel(const int* __restrict__ a0, int* __restrict__ r0,
                               const int* __restrict__ a1, int* __restrict__ r1,
                               const int* __restrict__ a2, int* __restrict__ r2) {
  const int* rows = (blockIdx.y == 0) ? a0 : (blockIdx.y == 1) ? a1 : a2;
  int* rp = (blockIdx.y == 0) ? r0 : (blockIdx.y == 1) ? r1 : r2;
  int i = blockIdx.x * blockDim.x + threadIdx.x;
  int stride = gridDim.x * blockDim.x;
  for (int t = i; t < NT; t += stride) {
    if (t == 0 || rows[t] != rows[t - 1]) rp[rows[t]] = t;
  }
  if (i == 0) rp[NN] = NT;
}

// ---------- per-relation tables ----------
__global__ __launch_bounds__(256) void relpre_kernel(
    const float* __restrict__ rel_emb, const float* __restrict__ attn_e,
    const float* __restrict__ attn_r, float4* __restrict__ e4,
    float4* __restrict__ tab0, float4* __restrict__ tab1) {
  int wid = (blockIdx.x * blockDim.x + threadIdx.x) >> 6;
  int lane = threadIdx.x & 63;
  if (wid >= NR) return;
  const float2* e2 = (const float2*)rel_emb;
  float2 e = e2[(size_t)wid * 64 + lane];
  float p = wsum64(e.x * e.x + e.y * e.y);  // norm^2
  float inv_n = rsqrtf(p);
  float n2i = 1.f / p;
  const float* ks[4] = {attn_e, attn_e + HID, attn_r, attn_r + HID};
  float d[4];
#pragma unroll
  for (int j = 0; j < 4; ++j) {
    float2 a = ((const float2*)ks[j])[lane];
    d[j] = wsum64(e.x * a.x + e.y * a.y);
  }
  if (lane == 0) {
    float4 ex = make_float4(expf(d[0] * inv_n), expf(d[1] * inv_n),
                            expf(d[2] * inv_n), expf(d[3] * inv_n));
    e4[wid] = ex;
    tab0[wid] = make_float4(ex.x, ex.z, n2i, 0.f);  // layer 0: (e, r, s2)
    tab1[wid] = make_float4(ex.y, ex.w, n2i, 0.f);  // layer 1
  }
}

// ---------- f32 -> fp16 mirrors of ent_emb and rel_emb ----------
__global__ __launch_bounds__(256) void cvt_kernel(const float* __restrict__ ent,
                                                  const float* __restrict__ rel,
                                                  __half* __restrict__ enth,
                                                  __half* __restrict__ relh) {
  int i = blockIdx.x * blockDim.x + threadIdx.x;  // (NN+NR)*16 units of 8 f32
  const int entu = NN * 16;
  const float4* s4;
  u32x4* d;
  int j;
  if (i < entu) {
    s4 = (const float4*)ent; d = (u32x4*)enth; j = i;
  } else {
    j = i - entu;
    if (j >= NR * 16) return;
    s4 = (const float4*)rel; d = (u32x4*)relh;
  }
  float4 a = s4[2 * j], b = s4[2 * j + 1];
  u32x4 w;
  w.x = pack2(a.x, a.y); w.y = pack2(a.z, a.w);
  w.z = pack2(b.x, b.y); w.w = pack2(b.z, b.w);
  __builtin_nontemporal_store(w, d + j);
}

// ---------- layer-0: segment mean + tanh; 2 nodes/wave; 2-deep pipeline ----------
__global__ __launch_bounds__(256) void avg_tanh_kernel(
    const int* __restrict__ rp_ent, const int* __restrict__ cols_ent,
    const int* __restrict__ rp_rel, const int* __restrict__ cols_rel,
    const __half* __restrict__ enth, const __half* __restrict__ relh,
    float* __restrict__ out, __half* __restrict__ c0h) {
  int wid = (blockIdx.x * blockDim.x + threadIdx.x) >> 6;
  int lane = threadIdx.x & 63;
  if (wid >= NN) return;  // 25000 node-pairs per branch
  int br = (wid >= NN / 2) ? 1 : 0;
  int pair = wid - br * (NN / 2);
  int node = pair * 2 + (lane >> 5);
  int sl = lane & 31;
  const int* rp = br ? rp_rel : rp_ent;
  const int* cols = br ? cols_rel : cols_ent;
  const u32x2* eb = (const u32x2*)(br ? relh : enth);
  int t0 = rp[node], t1 = rp[node + 1];
  int nmax = t1 - 1;

  // block-0 indices + stage-A gathers
  int c0 = cols[t0];
  int c1 = cols[min(t0 + 1, nmax)];
  int c2 = cols[min(t0 + 2, nmax)];
  int c3 = cols[min(t0 + 3, nmax)];
  u32x2 h0 = eb[(size_t)c0 * 32 + sl];
  u32x2 h1 = eb[(size_t)c1 * 32 + sl];
  u32x2 h2 = eb[(size_t)c2 * 32 + sl];
  u32x2 h3 = eb[(size_t)c3 * 32 + sl];
  // block-1 indices
  int d0 = cols[min(t0 + 4, nmax)];
  int d1 = cols[min(t0 + 5, nmax)];
  int d2 = cols[min(t0 + 6, nmax)];
  int d3 = cols[min(t0 + 7, nmax)];

  float4 acc = make_float4(0.f, 0.f, 0.f, 0.f);
  for (int t = t0; t < t1; t += 4) {
    // stage-B gathers (next block)
    u32x2 g0 = eb[(size_t)d0 * 32 + sl];
    u32x2 g1 = eb[(size_t)d1 * 32 + sl];
    u32x2 g2 = eb[(size_t)d2 * 32 + sl];
    u32x2 g3 = eb[(size_t)d3 * 32 + sl];
    // indices two blocks ahead
    int tm = t + 8;
    int n0 = cols[min(tm, nmax)];
    int n1 = cols[min(tm + 1, nmax)];
    int n2 = cols[min(tm + 2, nmax)];
    int n3 = cols[min(tm + 3, nmax)];
    // accumulate stage A
    float m1 = (t + 1 < t1) ? 1.f : 0.f;
    float m2 = (t + 2 < t1) ? 1.f : 0.f;
    float m3 = (t + 3 < t1) ? 1.f : 0.f;
    float2 a0 = unpack2(h0.x), b0v = unpack2(h0.y);
    float2 a1 = unpack2(h1.x), b1v = unpack2(h1.y);
    float2 a2 = unpack2(h2.x), b2v = unpack2(h2.y);
    float2 a3 = unpack2(h3.x), b3v = unpack2(h3.y);
    acc.x += a0.x + m1 * a1.x + m2 * a2.x + m3 * a3.x;
    acc.y += a0.y + m1 * a1.y + m2 * a2.y + m3 * a3.y;
    acc.z += b0v.x + m1 * b1v.x + m2 * b2v.x + m3 * b3v.x;
    acc.w += b0v.y + m1 * b1v.y + m2 * b2v.y + m3 * b3v.y;
    // rotate
    h0 = g0; h1 = g1; h2 = g2; h3 = g3;
    d0 = n0; d1 = n1; d2 = n2; d3 = n3;
  }
  float inv = 1.f / (float)(t1 - t0);
  float4 o;
  o.x = tanhf(acc.x * inv); o.y = tanhf(acc.y * inv);
  o.z = tanhf(acc.z * inv); o.w = tanhf(acc.w * inv);
  nt_store4(o, out + (size_t)node * OSTRIDE + (br ? 3 * HID : 0) + sl * 4);
  u32x2 w; w.x = pack2(o.x, o.y); w.y = pack2(o.z, o.w);
  __builtin_nontemporal_store(w, (u32x2*)(c0h + (size_t)node * CH + br * HID + sl * 4));
}

struct BlkT { int dn; int r; float tx, ty, n2i; };

__device__ __forceinline__ BlkT ldblk(int tb, int g, int t1,
                                      const int* __restrict__ dst,
                                      const int* __restrict__ rel_id,
                                      const float* __restrict__ r_val,
                                      const float4* __restrict__ tab) {
  int t = tb + g;
  bool valid = (t < t1);
  int tc = valid ? t : (t1 - 1);
  BlkT b;
  b.dn = dst[tc];
  b.r = rel_id[tc];
  float rv = r_val[tc];
  float4 tv = tab[b.r];
  if (rv <= 0.f) tv = make_float4(1.f, 1.f, 0.f, 0.f);  // zero-scale triple
  b.tx = valid ? tv.x : 0.f;
  b.ty = valid ? tv.y : 0.f;
  b.n2i = tv.z;
  return b;
}

__device__ __forceinline__ float dot8(const float4& a, const float4& b,
                                      const float4& c, const float4& d) {
  return a.x * c.x + a.y * c.y + a.z * c.z + a.w * c.w +
         b.x * d.x + b.y * d.y + b.z * d.z + b.w * d.w;
}
__device__ __forceinline__ void fma_acc(float4& a, float w, const float4& nb,
                                        float c, const float4& u) {
  a.x += w * nb.x + c * u.x;
  a.y += w * nb.y + c * u.y;
  a.z += w * nb.z + c * u.z;
  a.w += w * nb.w + c * u.w;
}
__device__ __forceinline__ float4 comb4(float4 a) {
  a.x += __shfl_xor(a.x, 16, 64); a.y += __shfl_xor(a.y, 16, 64);
  a.z += __shfl_xor(a.z, 16, 64); a.w += __shfl_xor(a.w, 16, 64);
  a.x += __shfl_xor(a.x, 32, 64); a.y += __shfl_xor(a.y, 32, 64);
  a.z += __shfl_xor(a.z, 32, 64); a.w += __shfl_xor(a.w, 32, 64);
  return a;
}

// ---------- one attention layer, both branches fused; 4 triples/iter;
// fp16 gathers; 2-deep pipeline (idx 2 ahead, feature rows 1 ahead) ----------
__global__ __launch_bounds__(256) void attn_kernel(
    float* __restrict__ out, const int* __restrict__ rp,
    const int* __restrict__ dst, const int* __restrict__ rel_id,
    const float* __restrict__ r_val, const float* __restrict__ rel_emb,
    const float4* __restrict__ tab, const float4* __restrict__ e4,
    float4* __restrict__ Sinv4, const __half* __restrict__ chin,
    __half* __restrict__ chout, int layer) {
  int wid = (blockIdx.x * blockDim.x + threadIdx.x) >> 6;
  int lane = threadIdx.x & 63;
  if (wid >= NN) return;
  int g = lane >> 4;   // triple slot 0..3
  int sl = lane & 15;  // dims [sl*8, sl*8+8)
  int t0 = rp[wid], t1 = rp[wid + 1];

  float sie, sir;
  if (layer == 0) {  // fused softmax-denominator pass
    float4 s = make_float4(0.f, 0.f, 0.f, 0.f);
    for (int t = t0 + lane; t < t1; t += 64) {
      int r = rel_id[t];
      float rv = r_val[t];
      float4 ex = e4[r];
      if (rv <= 0.f) ex = make_float4(1.f, 1.f, 1.f, 1.f);
      s.x += ex.x; s.y += ex.y; s.z += ex.z; s.w += ex.w;
    }
    s.x = wsum64(s.x); s.y = wsum64(s.y); s.z = wsum64(s.z); s.w = wsum64(s.w);
    float4 inv = make_float4(1.f / s.x, 1.f / s.y, 1.f / s.z, 1.f / s.w);
    if (lane == 0) Sinv4[wid] = inv;
    sie = inv.x; sir = inv.z;
  } else {
    float4 sv = Sinv4[wid];
    sie = sv.y; sir = sv.w;
  }

  // pipeline prologue
  BlkT b0 = ldblk(t0, g, t1, dst, rel_id, r_val, tab);
  const float4* up = (const float4*)(rel_emb + b0.r * HID + sl * 8);
  float4 u0 = up[0], u1 = up[1];
  const u32x4* ph = (const u32x4*)(chin + (size_t)b0.dn * CH);
  u32x4 eh = ph[sl], qh = ph[16 + sl];
  BlkT b1 = ldblk(t0 + 4, g, t1, dst, rel_id, r_val, tab);

  float4 ae0 = make_float4(0, 0, 0, 0), ae1 = ae0, ar0 = ae0, ar1 = ae0;

  for (int tb = t0; tb < t1; tb += 4) {
    // stage-B: issue next block's feature rows
    const float4* upN = (const float4*)(rel_emb + b1.r * HID + sl * 8);
    float4 u0N = upN[0], u1N = upN[1];
    const u32x4* phN = (const u32x4*)(chin + (size_t)b1.dn * CH);
    u32x4 ehN = phN[sl], qhN = phN[16 + sl];
    // indices two blocks ahead
    BlkT b2 = ldblk(tb + 8, g, t1, dst, rel_id, r_val, tab);

    // compute current block (b0)
    float2 p0 = unpack2(eh.x), p1 = unpack2(eh.y);
    float2 p2 = unpack2(eh.z), p3 = unpack2(eh.w);
    float4 e0 = make_float4(p0.x, p0.y, p1.x, p1.y);
    float4 e1 = make_float4(p2.x, p2.y, p3.x, p3.y);
    float2 r0v = unpack2(qh.x), r1v = unpack2(qh.y);
    float2 r2v = unpack2(qh.z), r3v = unpack2(qh.w);
    float4 q0 = make_float4(r0v.x, r0v.y, r1v.x, r1v.y);
    float4 q1 = make_float4(r2v.x, r2v.y, r3v.x, r3v.y);

    float de = dot8(u0, u1, e0, e1);
    float dr = dot8(u0, u1, q0, q1);
#pragma unroll
    for (int off = 1; off < 16; off <<= 1) {
      de += __shfl_xor(de, off, 64);
      dr += __shfl_xor(dr, off, 64);
    }
    float we = b0.tx * sie;
    float wr = b0.ty * sir;
    float ce = -2.f * we * b0.n2i * de;
    float cr = -2.f * wr * b0.n2i * dr;
    fma_acc(ae0, we, e0, ce, u0);
    fma_acc(ae1, we, e1, ce, u1);
    fma_acc(ar0, wr, q0, cr, u0);
    fma_acc(ar1, wr, q1, cr, u1);

    // rotate pipeline
    b0 = b1; b1 = b2;
    u0 = u0N; u1 = u1N; eh = ehN; qh = qhN;
  }

  ae0 = comb4(ae0); ae1 = comb4(ae1); ar0 = comb4(ar0); ar1 = comb4(ar1);

  float4 v;
  if (g == 0) v = ae0;
  else if (g == 1) v = ae1;
  else if (g == 2) v = ar0;
  else v = ar1;
  v.x = tanhf(v.x); v.y = tanhf(v.y); v.z = tanhf(v.z); v.w = tanhf(v.w);
  float* ob = (g < 2) ? (out + (size_t)wid * OSTRIDE + (layer + 1) * HID)
                      : (out + (size_t)wid * OSTRIDE + (4 + layer) * HID);
  nt_store4(v, ob + sl * 8 + (g & 1) * 4);
  if (chout) {
    u32x2 w; w.x = pack2(v.x, v.y); w.y = pack2(v.z, v.w);
    __builtin_nontemporal_store(
        w, (u32x2*)(chout + (size_t)wid * CH + (g >> 1) * 128 + sl * 8 + (g & 1) * 4));
  }
}

extern "C" void kernel_launch(void* const* d_in, const int* in_sizes, int n_in,
                              void* d_out, int out_size, void* d_ws, size_t ws_size,
                              hipStream_t stream) {
  const float* ent_emb = (const float*)d_in[0];
  const float* rel_emb = (const float*)d_in[1];
  const float* attn_e = (const float*)d_in[2];
  const float* attn_r = (const float*)d_in[3];
  const int* adj = (const int*)d_in[4];
  const int* r_index = (const int*)d_in[5];
  const float* r_val = (const float*)d_in[6];
  const int* ent_adj = (const int*)d_in[7];
  const int* rel_adj = (const int*)d_in[8];
  float* out = (float*)d_out;

  char* ws = (char*)d_ws;
  __half* enth = (__half*)ws;  ws += (size_t)NN * HID * sizeof(__half);  // 12.8 MB
  __half* relh = (__half*)ws;  ws += (size_t)NR * HID * sizeof(__half);  // 0.5 MB
  __half* C0h = (__half*)ws;   ws += (size_t)NN * CH * sizeof(__half);   // 25.6 MB
  __half* C1h = (__half*)ws;   ws += (size_t)NN * CH * sizeof(__half);   // 25.6 MB
  float4* e4 = (float4*)ws;    ws += (size_t)NR * sizeof(float4);
  float4* tab0 = (float4*)ws;  ws += (size_t)NR * sizeof(float4);
  float4* tab1 = (float4*)ws;  ws += (size_t)NR * sizeof(float4);
  float4* Sinv4 = (float4*)ws; ws += (size_t)NN * sizeof(float4);
  int* rp_adj = (int*)ws;      ws += (NN + 1) * sizeof(int);
  int* rp_ent = (int*)ws;      ws += (NN + 1) * sizeof(int);
  int* rp_rel = (int*)ws;      ws += (NN + 1) * sizeof(int);

  dim3 rg(512, 3);
  rowptr3_kernel<<<rg, 256, 0, stream>>>(adj, rp_adj, ent_adj, rp_ent, rel_adj, rp_rel);
  relpre_kernel<<<(NR * 64) / 256, 256, 0, stream>>>(rel_emb, attn_e, attn_r,
                                                     e4, tab0, tab1);
  cvt_kernel<<<((NN + NR) * 16) / 256, 256, 0, stream>>>(ent_emb, rel_emb, enth, relh);
  avg_tanh_kernel<<<(NN * 64) / 256, 256, 0, stream>>>(
      rp_ent, ent_adj + NT, rp_rel, rel_adj + NT, enth, relh, out, C0h);
  for (int l = 0; l < 2; ++l) {
    attn_kernel<<<(NN * 64) / 256, 256, 0, stream>>>(
        out, rp_adj, adj + NT, r_index + NT, r_val, rel_emb,
        (l == 0) ? tab0 : tab1, e4, Sinv4, (l == 0) ? C0h : C1h,
        (l == 0) ? C1h : nullptr, l);
  }
}

// Round 7
// 468.467 us; speedup vs baseline: 1.0396x; 1.0396x over previous
//
#include <hip/hip_runtime.h>
#include <hip/hip_fp16.h>
#include <math.h>

#define NN 50000
#define NR 2000
#define NT 1000000
#define HID 128
#define OSTRIDE 768
#define CH 256  // halves per compact feature row (e:0..127, r:128..255)

typedef float f32x4 __attribute__((ext_vector_type(4)));
typedef unsigned u32x4 __attribute__((ext_vector_type(4)));
typedef unsigned u32x2 __attribute__((ext_vector_type(2)));
typedef _Float16 h16x2 __attribute__((ext_vector_type(2)));
typedef _Float16 h16x8 __attribute__((ext_vector_type(8)));

union U4H8 { u32x4 u; h16x8 h; };

__device__ __forceinline__ float wsum64(float v) {
#pragma unroll
  for (int off = 32; off > 0; off >>= 1) v += __shfl_xor(v, off, 64);
  return v;
}
__device__ __forceinline__ unsigned pack2(float x, float y) {
  __half2 h = __floats2half2_rn(x, y);
  union { __half2 h; unsigned u; } c; c.h = h; return c.u;
}
__device__ __forceinline__ float2 unpack2(unsigned u) {
  union { unsigned u; __half2 h; } c; c.u = u;
  return __half22float2(c.h);
}
__device__ __forceinline__ void nt_store4(const float4& v, float* p) {
  f32x4 t = {v.x, v.y, v.z, v.w};
  __builtin_nontemporal_store(t, (f32x4*)p);
}

// ---------- row pointers for all three sorted covering adjacencies ----------
__global__ void rowptr3_kernel(const int* __restrict__ a0, int* __restrict__ r0,
                               const int* __restrict__ a1, int* __restrict__ r1,
                               const int* __restrict__ a2, int* __restrict__ r2) {
  const int* rows = (blockIdx.y == 0) ? a0 : (blockIdx.y == 1) ? a1 : a2;
  int* rp = (blockIdx.y == 0) ? r0 : (blockIdx.y == 1) ? r1 : r2;
  int i = blockIdx.x * blockDim.x + threadIdx.x;
  int stride = gridDim.x * blockDim.x;
  for (int t = i; t < NT; t += stride) {
    if (t == 0 || rows[t] != rows[t - 1]) rp[rows[t]] = t;
  }
  if (i == 0) rp[NN] = NT;
}

// ---------- per-relation: exp(attdot/norm) for 4 kernels + 1/norm^2 ----------
__global__ __launch_bounds__(256) void relpre_kernel(
    const float* __restrict__ rel_emb, const float* __restrict__ attn_e,
    const float* __restrict__ attn_r, float4* __restrict__ e4,
    float* __restrict__ n2i_arr) {
  int wid = (blockIdx.x * blockDim.x + threadIdx.x) >> 6;
  int lane = threadIdx.x & 63;
  if (wid >= NR) return;
  const float2* e2 = (const float2*)rel_emb;
  float2 e = e2[(size_t)wid * 64 + lane];
  float p = wsum64(e.x * e.x + e.y * e.y);  // norm^2
  float inv_n = rsqrtf(p);
  const float* ks[4] = {attn_e, attn_e + HID, attn_r, attn_r + HID};
  float d[4];
#pragma unroll
  for (int j = 0; j < 4; ++j) {
    float2 a = ((const float2*)ks[j])[lane];
    d[j] = wsum64(e.x * a.x + e.y * a.y);
  }
  if (lane == 0) {
    e4[wid] = make_float4(expf(d[0] * inv_n), expf(d[1] * inv_n),
                          expf(d[2] * inv_n), expf(d[3] * inv_n));
    n2i_arr[wid] = 1.f / p;
  }
}

// ---------- f32 -> fp16 mirrors of ent_emb and rel_emb ----------
__global__ __launch_bounds__(256) void cvt_kernel(const float* __restrict__ ent,
                                                  const float* __restrict__ rel,
                                                  __half* __restrict__ enth,
                                                  __half* __restrict__ relh) {
  int i = blockIdx.x * blockDim.x + threadIdx.x;  // (NN+NR)*16 units of 8 f32
  const int entu = NN * 16;
  const float4* s4;
  u32x4* d;
  int j;
  if (i < entu) {
    s4 = (const float4*)ent; d = (u32x4*)enth; j = i;
  } else {
    j = i - entu;
    if (j >= NR * 16) return;
    s4 = (const float4*)rel; d = (u32x4*)relh;
  }
  float4 a = s4[2 * j], b = s4[2 * j + 1];
  u32x4 w;
  w.x = pack2(a.x, a.y); w.y = pack2(a.z, a.w);
  w.z = pack2(b.x, b.y); w.w = pack2(b.z, b.w);
  __builtin_nontemporal_store(w, d + j);
}

// ---------- per-triple packed records: pk = dn | (r<<16); wq_l = half4{we,wr,cwe,cwr} ----------
__global__ __launch_bounds__(256) void wpre2_kernel(
    const int* __restrict__ rp, const int* __restrict__ dst,
    const int* __restrict__ rel_id, const float* __restrict__ r_val,
    const float4* __restrict__ e4, const float* __restrict__ n2i_arr,
    unsigned* __restrict__ pk, u32x2* __restrict__ wq0,
    u32x2* __restrict__ wq1) {
  int wid = (blockIdx.x * blockDim.x + threadIdx.x) >> 6;
  int lane = threadIdx.x & 63;
  if (wid >= NN) return;
  int t0 = rp[wid], t1 = rp[wid + 1];
  // pass 1: softmax denominators (no max needed: att bounded, shift-invariant)
  float4 s = make_float4(0.f, 0.f, 0.f, 0.f);
  for (int t = t0 + lane; t < t1; t += 64) {
    int r = rel_id[t];
    float rv = r_val[t];
    float4 ex = e4[r];
    if (rv <= 0.f) ex = make_float4(1.f, 1.f, 1.f, 1.f);
    s.x += ex.x; s.y += ex.y; s.z += ex.z; s.w += ex.w;
  }
  s.x = wsum64(s.x); s.y = wsum64(s.y); s.z = wsum64(s.z); s.w = wsum64(s.w);
  float4 inv = make_float4(1.f / s.x, 1.f / s.y, 1.f / s.z, 1.f / s.w);
  // pass 2: write records
  for (int t = t0 + lane; t < t1; t += 64) {
    int r = rel_id[t];
    float rv = r_val[t];
    int dn = dst[t];
    float4 ex = e4[r];
    float zi = n2i_arr[r];
    if (rv <= 0.f) { ex = make_float4(1.f, 1.f, 1.f, 1.f); zi = 0.f; }
    float we0 = ex.x * inv.x, wr0 = ex.z * inv.z;
    float we1 = ex.y * inv.y, wr1 = ex.w * inv.w;
    __builtin_nontemporal_store((unsigned)dn | ((unsigned)r << 16), pk + t);
    u32x2 a, b;
    a.x = pack2(we0, wr0); a.y = pack2(-2.f * we0 * zi, -2.f * wr0 * zi);
    b.x = pack2(we1, wr1); b.y = pack2(-2.f * we1 * zi, -2.f * wr1 * zi);
    __builtin_nontemporal_store(a, wq0 + t);
    __builtin_nontemporal_store(b, wq1 + t);
  }
}

// ---------- layer-0: segment mean + tanh; 2 nodes/wave; 2-deep pipeline ----------
__global__ __launch_bounds__(256) void avg_tanh_kernel(
    const int* __restrict__ rp_ent, const int* __restrict__ cols_ent,
    const int* __restrict__ rp_rel, const int* __restrict__ cols_rel,
    const __half* __restrict__ enth, const __half* __restrict__ relh,
    float* __restrict__ out, __half* __restrict__ c0h) {
  int wid = (blockIdx.x * blockDim.x + threadIdx.x) >> 6;
  int lane = threadIdx.x & 63;
  if (wid >= NN) return;  // 25000 node-pairs per branch
  int br = (wid >= NN / 2) ? 1 : 0;
  int pair = wid - br * (NN / 2);
  int node = pair * 2 + (lane >> 5);
  int sl = lane & 31;
  const int* rp = br ? rp_rel : rp_ent;
  const int* cols = br ? cols_rel : cols_ent;
  const u32x2* eb = (const u32x2*)(br ? relh : enth);
  int t0 = rp[node], t1 = rp[node + 1];
  int nmax = t1 - 1;

  int c0 = cols[t0];
  int c1 = cols[min(t0 + 1, nmax)];
  int c2 = cols[min(t0 + 2, nmax)];
  int c3 = cols[min(t0 + 3, nmax)];
  u32x2 h0 = eb[(size_t)c0 * 32 + sl];
  u32x2 h1 = eb[(size_t)c1 * 32 + sl];
  u32x2 h2 = eb[(size_t)c2 * 32 + sl];
  u32x2 h3 = eb[(size_t)c3 * 32 + sl];
  int d0 = cols[min(t0 + 4, nmax)];
  int d1 = cols[min(t0 + 5, nmax)];
  int d2 = cols[min(t0 + 6, nmax)];
  int d3 = cols[min(t0 + 7, nmax)];

  float4 acc = make_float4(0.f, 0.f, 0.f, 0.f);
  for (int t = t0; t < t1; t += 4) {
    u32x2 g0 = eb[(size_t)d0 * 32 + sl];
    u32x2 g1 = eb[(size_t)d1 * 32 + sl];
    u32x2 g2 = eb[(size_t)d2 * 32 + sl];
    u32x2 g3 = eb[(size_t)d3 * 32 + sl];
    int tm = t + 8;
    int n0 = cols[min(tm, nmax)];
    int n1 = cols[min(tm + 1, nmax)];
    int n2 = cols[min(tm + 2, nmax)];
    int n3 = cols[min(tm + 3, nmax)];
    float m1 = (t + 1 < t1) ? 1.f : 0.f;
    float m2 = (t + 2 < t1) ? 1.f : 0.f;
    float m3 = (t + 3 < t1) ? 1.f : 0.f;
    float2 a0 = unpack2(h0.x), b0v = unpack2(h0.y);
    float2 a1 = unpack2(h1.x), b1v = unpack2(h1.y);
    float2 a2 = unpack2(h2.x), b2v = unpack2(h2.y);
    float2 a3 = unpack2(h3.x), b3v = unpack2(h3.y);
    acc.x += a0.x + m1 * a1.x + m2 * a2.x + m3 * a3.x;
    acc.y += a0.y + m1 * a1.y + m2 * a2.y + m3 * a3.y;
    acc.z += b0v.x + m1 * b1v.x + m2 * b2v.x + m3 * b3v.x;
    acc.w += b0v.y + m1 * b1v.y + m2 * b2v.y + m3 * b3v.y;
    h0 = g0; h1 = g1; h2 = g2; h3 = g3;
    d0 = n0; d1 = n1; d2 = n2; d3 = n3;
  }
  float inv = 1.f / (float)(t1 - t0);
  float4 o;
  o.x = tanhf(acc.x * inv); o.y = tanhf(acc.y * inv);
  o.z = tanhf(acc.z * inv); o.w = tanhf(acc.w * inv);
  nt_store4(o, out + (size_t)node * OSTRIDE + (br ? 3 * HID : 0) + sl * 4);
  u32x2 w; w.x = pack2(o.x, o.y); w.y = pack2(o.z, o.w);
  __builtin_nontemporal_store(w, (u32x2*)(c0h + (size_t)node * CH + br * HID + sl * 4));
}

struct RecT { int dn; int r; float we, wr, ce, cr; };

__device__ __forceinline__ RecT ldrec(int t, int t1,
                                      const unsigned* __restrict__ pk,
                                      const u32x2* __restrict__ wq) {
  bool valid = (t < t1);
  int tc = valid ? t : (t1 - 1);
  unsigned p = pk[tc];
  u32x2 w = wq[tc];
  RecT rec;
  rec.dn = (int)(p & 0xFFFFu);
  rec.r = (int)(p >> 16);
  float2 a = unpack2(w.x);
  float2 b = unpack2(w.y);
  rec.we = valid ? a.x : 0.f;
  rec.wr = valid ? a.y : 0.f;
  rec.ce = valid ? b.x : 0.f;
  rec.cr = valid ? b.y : 0.f;
  return rec;
}

// ---------- one attention layer, both branches fused; 4 triples/iter;
// all-fp16 gathers, packed per-triple records, index prefetch ----------
__global__ __launch_bounds__(256) void attn_kernel(
    float* __restrict__ out, const int* __restrict__ rp,
    const unsigned* __restrict__ pk, const u32x2* __restrict__ wq,
    const __half* __restrict__ relh, const __half* __restrict__ chin,
    __half* __restrict__ chout, int layer) {
  int wid = (blockIdx.x * blockDim.x + threadIdx.x) >> 6;
  int lane = threadIdx.x & 63;
  if (wid >= NN) return;
  int g = lane >> 4;   // triple slot 0..3
  int sl = lane & 15;  // dims [sl*8, sl*8+8)
  int t0 = rp[wid], t1 = rp[wid + 1];

  const u32x4* relh4 = (const u32x4*)relh;
  RecT b0 = ldrec(t0 + g, t1, pk, wq);
  float aE[8], aR[8];
#pragma unroll
  for (int i = 0; i < 8; ++i) { aE[i] = 0.f; aR[i] = 0.f; }

  for (int tb = t0; tb < t1; tb += 4) {
    U4H8 uh, eh, qh;
    uh.u = relh4[(size_t)b0.r * 16 + sl];
    const u32x4* ph = (const u32x4*)chin + (size_t)b0.dn * 32;
    eh.u = ph[sl];
    qh.u = ph[16 + sl];
    RecT b1 = ldrec(tb + 4 + g, t1, pk, wq);

    float de = 0.f, dr = 0.f;
#if __has_builtin(__builtin_amdgcn_fdot2)
#pragma unroll
    for (int i = 0; i < 4; ++i) {
      h16x2 up = {uh.h[2 * i], uh.h[2 * i + 1]};
      h16x2 ep = {eh.h[2 * i], eh.h[2 * i + 1]};
      h16x2 qp = {qh.h[2 * i], qh.h[2 * i + 1]};
      de = __builtin_amdgcn_fdot2(up, ep, de, false);
      dr = __builtin_amdgcn_fdot2(up, qp, dr, false);
    }
#else
#pragma unroll
    for (int i = 0; i < 8; ++i) {
      de += (float)uh.h[i] * (float)eh.h[i];
      dr += (float)uh.h[i] * (float)qh.h[i];
    }
#endif
#pragma unroll
    for (int off = 1; off < 16; off <<= 1) {
      de += __shfl_xor(de, off, 64);
      dr += __shfl_xor(dr, off, 64);
    }
    float ce = b0.ce * de;  // b0.ce = -2*we/||e_r||^2
    float cr = b0.cr * dr;
#pragma unroll
    for (int i = 0; i < 8; ++i) {
      float uf = (float)uh.h[i];
      aE[i] += b0.we * (float)eh.h[i] + ce * uf;
      aR[i] += b0.wr * (float)qh.h[i] + cr * uf;
    }
    b0 = b1;
  }

#pragma unroll
  for (int i = 0; i < 8; ++i) {
    aE[i] += __shfl_xor(aE[i], 16, 64);
    aE[i] += __shfl_xor(aE[i], 32, 64);
    aR[i] += __shfl_xor(aR[i], 16, 64);
    aR[i] += __shfl_xor(aR[i], 32, 64);
  }

  float4 v;
  if (g == 0) v = make_float4(aE[0], aE[1], aE[2], aE[3]);
  else if (g == 1) v = make_float4(aE[4], aE[5], aE[6], aE[7]);
  else if (g == 2) v = make_float4(aR[0], aR[1], aR[2], aR[3]);
  else v = make_float4(aR[4], aR[5], aR[6], aR[7]);
  v.x = tanhf(v.x); v.y = tanhf(v.y); v.z = tanhf(v.z); v.w = tanhf(v.w);
  float* ob = (g < 2) ? (out + (size_t)wid * OSTRIDE + (layer + 1) * HID)
                      : (out + (size_t)wid * OSTRIDE + (4 + layer) * HID);
  nt_store4(v, ob + sl * 8 + (g & 1) * 4);
  if (chout) {
    u32x2 w; w.x = pack2(v.x, v.y); w.y = pack2(v.z, v.w);
    __builtin_nontemporal_store(
        w, (u32x2*)(chout + (size_t)wid * CH + (g >> 1) * 128 + sl * 8 + (g & 1) * 4));
  }
}

extern "C" void kernel_launch(void* const* d_in, const int* in_sizes, int n_in,
                              void* d_out, int out_size, void* d_ws, size_t ws_size,
                              hipStream_t stream) {
  const float* ent_emb = (const float*)d_in[0];
  const float* rel_emb = (const float*)d_in[1];
  const float* attn_e = (const float*)d_in[2];
  const float* attn_r = (const float*)d_in[3];
  const int* adj = (const int*)d_in[4];
  const int* r_index = (const int*)d_in[5];
  const float* r_val = (const float*)d_in[6];
  const int* ent_adj = (const int*)d_in[7];
  const int* rel_adj = (const int*)d_in[8];
  float* out = (float*)d_out;

  char* ws = (char*)d_ws;
  __half* enth = (__half*)ws;  ws += (size_t)NN * HID * sizeof(__half);  // 12.8 MB
  __half* relh = (__half*)ws;  ws += (size_t)NR * HID * sizeof(__half);  // 0.5 MB
  __half* C0h = (__half*)ws;   ws += (size_t)NN * CH * sizeof(__half);   // 25.6 MB
  __half* C1h = (__half*)ws;   ws += (size_t)NN * CH * sizeof(__half);   // 25.6 MB
  unsigned* pk = (unsigned*)ws; ws += (size_t)NT * sizeof(unsigned);     // 4 MB
  u32x2* wq0 = (u32x2*)ws;     ws += (size_t)NT * sizeof(u32x2);         // 8 MB
  u32x2* wq1 = (u32x2*)ws;     ws += (size_t)NT * sizeof(u32x2);         // 8 MB
  float4* e4 = (float4*)ws;    ws += (size_t)NR * sizeof(float4);
  float* n2i = (float*)ws;     ws += (size_t)NR * sizeof(float);
  int* rp_adj = (int*)ws;      ws += (NN + 1) * sizeof(int);
  int* rp_ent = (int*)ws;      ws += (NN + 1) * sizeof(int);
  int* rp_rel = (int*)ws;      ws += (NN + 1) * sizeof(int);

  dim3 rg(512, 3);
  rowptr3_kernel<<<rg, 256, 0, stream>>>(adj, rp_adj, ent_adj, rp_ent, rel_adj, rp_rel);
  relpre_kernel<<<(NR * 64) / 256, 256, 0, stream>>>(rel_emb, attn_e, attn_r, e4, n2i);
  cvt_kernel<<<((NN + NR) * 16) / 256, 256, 0, stream>>>(ent_emb, rel_emb, enth, relh);
  wpre2_kernel<<<(NN * 64) / 256, 256, 0, stream>>>(
      rp_adj, adj + NT, r_index + NT, r_val, e4, n2i, pk, wq0, wq1);
  avg_tanh_kernel<<<(NN * 64) / 256, 256, 0, stream>>>(
      rp_ent, ent_adj + NT, rp_rel, rel_adj + NT, enth, relh, out, C0h);
  for (int l = 0; l < 2; ++l) {
    attn_kernel<<<(NN * 64) / 256, 256, 0, stream>>>(
        out, rp_adj, pk, (l == 0) ? wq0 : wq1, relh,
        (l == 0) ? C0h : C1h, (l == 0) ? C1h : nullptr, l);
  }
}

// Round 9
// 467.731 us; speedup vs baseline: 1.0413x; 1.0016x over previous
//
#include <hip/hip_runtime.h>
#include <hip/hip_fp16.h>
#include <math.h>

#define NN 50000
#define NR 2000
#define NT 1000000
#define HID 128
#define OSTRIDE 768
#define CH 256  // halves per compact feature row (e:0..127, r:128..255)

typedef float f32x4 __attribute__((ext_vector_type(4)));
typedef unsigned u32x4 __attribute__((ext_vector_type(4)));
typedef unsigned u32x2 __attribute__((ext_vector_type(2)));
typedef _Float16 h16x2 __attribute__((ext_vector_type(2)));
typedef _Float16 h16x8 __attribute__((ext_vector_type(8)));

union U4H8 { u32x4 u; h16x8 h; };

__device__ __forceinline__ float wsum64(float v) {
#pragma unroll
  for (int off = 32; off > 0; off >>= 1) v += __shfl_xor(v, off, 64);
  return v;
}
__device__ __forceinline__ unsigned pack2(float x, float y) {
  __half2 h = __floats2half2_rn(x, y);
  union { __half2 h; unsigned u; } c; c.h = h; return c.u;
}
__device__ __forceinline__ float2 unpack2(unsigned u) {
  union { unsigned u; __half2 h; } c; c.u = u;
  return __half22float2(c.h);
}
__device__ __forceinline__ void nt_store4(const float4& v, float* p) {
  f32x4 t = {v.x, v.y, v.z, v.w};
  __builtin_nontemporal_store(t, (f32x4*)p);
}

// ---------- row pointers for all three sorted covering adjacencies ----------
__global__ void rowptr3_kernel(const int* __restrict__ a0, int* __restrict__ r0,
                               const int* __restrict__ a1, int* __restrict__ r1,
                               const int* __restrict__ a2, int* __restrict__ r2) {
  const int* rows = (blockIdx.y == 0) ? a0 : (blockIdx.y == 1) ? a1 : a2;
  int* rp = (blockIdx.y == 0) ? r0 : (blockIdx.y == 1) ? r1 : r2;
  int i = blockIdx.x * blockDim.x + threadIdx.x;
  int stride = gridDim.x * blockDim.x;
  for (int t = i; t < NT; t += stride) {
    if (t == 0 || rows[t] != rows[t - 1]) rp[rows[t]] = t;
  }
  if (i == 0) rp[NN] = NT;
}

// ---------- prep: per-relation tables (waves 0..NR-1) + fp16 mirrors (rest) ----------
__global__ __launch_bounds__(256) void prep_kernel(
    const float* __restrict__ rel_emb, const float* __restrict__ attn_e,
    const float* __restrict__ attn_r, float4* __restrict__ e4,
    float* __restrict__ n2i_arr, const float* __restrict__ ent_emb,
    __half* __restrict__ enth, __half* __restrict__ relh) {
  int wid = (blockIdx.x * blockDim.x + threadIdx.x) >> 6;
  int lane = threadIdx.x & 63;
  if (wid < NR) {  // relpre role
    const float2* e2 = (const float2*)rel_emb;
    float2 e = e2[(size_t)wid * 64 + lane];
    float p = wsum64(e.x * e.x + e.y * e.y);  // norm^2
    float inv_n = rsqrtf(p);
    const float* ks[4] = {attn_e, attn_e + HID, attn_r, attn_r + HID};
    float d[4];
#pragma unroll
    for (int j = 0; j < 4; ++j) {
      float2 a = ((const float2*)ks[j])[lane];
      d[j] = wsum64(e.x * a.x + e.y * a.y);
    }
    if (lane == 0) {
      e4[wid] = make_float4(expf(d[0] * inv_n), expf(d[1] * inv_n),
                            expf(d[2] * inv_n), expf(d[3] * inv_n));
      n2i_arr[wid] = 1.f / p;
    }
    return;
  }
  // cvt role: unit i covers 8 f32
  int i = (wid - NR) * 64 + lane;
  const int entu = NN * 16;
  const float4* s4;
  u32x4* d;
  int j;
  if (i < entu) {
    s4 = (const float4*)ent_emb; d = (u32x4*)enth; j = i;
  } else {
    j = i - entu;
    if (j >= NR * 16) return;
    s4 = (const float4*)rel_emb; d = (u32x4*)relh;
  }
  float4 a = s4[2 * j], b = s4[2 * j + 1];
  u32x4 w;
  w.x = pack2(a.x, a.y); w.y = pack2(a.z, a.w);
  w.z = pack2(b.x, b.y); w.w = pack2(b.z, b.w);
  __builtin_nontemporal_store(w, d + j);
}

// ---------- fused: layer-0 segment mean+tanh (waves 0..NN-1, 8 rows/iter)
//            + per-triple record precompute (next NN/4 waves, 16 lanes/node) ----------
__global__ __launch_bounds__(256) void avgwpre_kernel(
    const int* __restrict__ rp_ent, const int* __restrict__ cols_ent,
    const int* __restrict__ rp_rel, const int* __restrict__ cols_rel,
    const __half* __restrict__ enth, const __half* __restrict__ relh,
    float* __restrict__ out, __half* __restrict__ c0h,
    const int* __restrict__ rp_adj, const int* __restrict__ dst,
    const int* __restrict__ rel_id, const float* __restrict__ r_val,
    const float4* __restrict__ e4, const float* __restrict__ n2i_arr,
    unsigned* __restrict__ pk, u32x2* __restrict__ wq0,
    u32x2* __restrict__ wq1) {
  int wid = (blockIdx.x * blockDim.x + threadIdx.x) >> 6;
  int lane = threadIdx.x & 63;

  if (wid < NN) {  // ---- avg role: 2 nodes/wave, 8 rows in flight per node ----
    int br = (wid >= NN / 2) ? 1 : 0;
    int pair = wid - br * (NN / 2);
    int node = pair * 2 + (lane >> 5);
    int sl = lane & 31;
    const int* rp = br ? rp_rel : rp_ent;
    const int* cols = br ? cols_rel : cols_ent;
    const u32x2* eb = (const u32x2*)(br ? relh : enth);
    int t0 = rp[node], t1 = rp[node + 1];
    int nmax = t1 - 1;
    int i0 = cols[t0];
    int i1 = cols[min(t0 + 1, nmax)];
    int i2 = cols[min(t0 + 2, nmax)];
    int i3 = cols[min(t0 + 3, nmax)];
    int i4 = cols[min(t0 + 4, nmax)];
    int i5 = cols[min(t0 + 5, nmax)];
    int i6 = cols[min(t0 + 6, nmax)];
    int i7 = cols[min(t0 + 7, nmax)];
    float4 acc = make_float4(0.f, 0.f, 0.f, 0.f);
    const u32x2 z = {0u, 0u};
    for (int t = t0; t < t1; t += 8) {
      u32x2 h0 = eb[(size_t)i0 * 32 + sl];
      u32x2 h1 = eb[(size_t)i1 * 32 + sl];
      u32x2 h2 = eb[(size_t)i2 * 32 + sl];
      u32x2 h3 = eb[(size_t)i3 * 32 + sl];
      u32x2 h4 = eb[(size_t)i4 * 32 + sl];
      u32x2 h5 = eb[(size_t)i5 * 32 + sl];
      u32x2 h6 = eb[(size_t)i6 * 32 + sl];
      u32x2 h7 = eb[(size_t)i7 * 32 + sl];
      int tn = t + 8;
      i0 = cols[min(tn, nmax)];
      i1 = cols[min(tn + 1, nmax)];
      i2 = cols[min(tn + 2, nmax)];
      i3 = cols[min(tn + 3, nmax)];
      i4 = cols[min(tn + 4, nmax)];
      i5 = cols[min(tn + 5, nmax)];
      i6 = cols[min(tn + 6, nmax)];
      i7 = cols[min(tn + 7, nmax)];
      h1 = (t + 1 < t1) ? h1 : z;
      h2 = (t + 2 < t1) ? h2 : z;
      h3 = (t + 3 < t1) ? h3 : z;
      h4 = (t + 4 < t1) ? h4 : z;
      h5 = (t + 5 < t1) ? h5 : z;
      h6 = (t + 6 < t1) ? h6 : z;
      h7 = (t + 7 < t1) ? h7 : z;
      float2 a0 = unpack2(h0.x), b0 = unpack2(h0.y);
      float2 a1 = unpack2(h1.x), b1 = unpack2(h1.y);
      float2 a2 = unpack2(h2.x), b2 = unpack2(h2.y);
      float2 a3 = unpack2(h3.x), b3 = unpack2(h3.y);
      float2 a4 = unpack2(h4.x), b4 = unpack2(h4.y);
      float2 a5 = unpack2(h5.x), b5 = unpack2(h5.y);
      float2 a6 = unpack2(h6.x), b6 = unpack2(h6.y);
      float2 a7 = unpack2(h7.x), b7 = unpack2(h7.y);
      acc.x += ((a0.x + a1.x) + (a2.x + a3.x)) + ((a4.x + a5.x) + (a6.x + a7.x));
      acc.y += ((a0.y + a1.y) + (a2.y + a3.y)) + ((a4.y + a5.y) + (a6.y + a7.y));
      acc.z += ((b0.x + b1.x) + (b2.x + b3.x)) + ((b4.x + b5.x) + (b6.x + b7.x));
      acc.w += ((b0.y + b1.y) + (b2.y + b3.y)) + ((b4.y + b5.y) + (b6.y + b7.y));
    }
    float inv = 1.f / (float)(t1 - t0);
    float4 o;
    o.x = tanhf(acc.x * inv); o.y = tanhf(acc.y * inv);
    o.z = tanhf(acc.z * inv); o.w = tanhf(acc.w * inv);
    nt_store4(o, out + (size_t)node * OSTRIDE + (br ? 3 * HID : 0) + sl * 4);
    u32x2 w; w.x = pack2(o.x, o.y); w.y = pack2(o.z, o.w);
    __builtin_nontemporal_store(w,
        (u32x2*)(c0h + (size_t)node * CH + br * HID + sl * 4));
    return;
  }

  wid -= NN;
  if (wid >= NN / 4) return;
  // ---- wpre role: 4 nodes/wave, 16 lanes per node ----
  int sub = lane >> 4;
  int s = lane & 15;
  int node = wid * 4 + sub;
  int t0 = rp_adj[node], t1 = rp_adj[node + 1];
  float4 ss = make_float4(0.f, 0.f, 0.f, 0.f);
  for (int t = t0 + s; t < t1; t += 16) {
    int r = rel_id[t];
    float rv = r_val[t];
    float4 ex = e4[r];
    if (rv <= 0.f) ex = make_float4(1.f, 1.f, 1.f, 1.f);
    ss.x += ex.x; ss.y += ex.y; ss.z += ex.z; ss.w += ex.w;
  }
#pragma unroll
  for (int off = 1; off < 16; off <<= 1) {
    ss.x += __shfl_xor(ss.x, off, 64);
    ss.y += __shfl_xor(ss.y, off, 64);
    ss.z += __shfl_xor(ss.z, off, 64);
    ss.w += __shfl_xor(ss.w, off, 64);
  }
  float4 inv = make_float4(1.f / ss.x, 1.f / ss.y, 1.f / ss.z, 1.f / ss.w);
  for (int t = t0 + s; t < t1; t += 16) {
    int r = rel_id[t];
    float rv = r_val[t];
    int dn = dst[t];
    float4 ex = e4[r];
    float zi = n2i_arr[r];
    if (rv <= 0.f) { ex = make_float4(1.f, 1.f, 1.f, 1.f); zi = 0.f; }
    float we0 = ex.x * inv.x, wr0 = ex.z * inv.z;
    float we1 = ex.y * inv.y, wr1 = ex.w * inv.w;
    __builtin_nontemporal_store((unsigned)dn | ((unsigned)r << 16), pk + t);
    u32x2 a, b;
    a.x = pack2(we0, wr0); a.y = pack2(-2.f * we0 * zi, -2.f * wr0 * zi);
    b.x = pack2(we1, wr1); b.y = pack2(-2.f * we1 * zi, -2.f * wr1 * zi);
    __builtin_nontemporal_store(a, wq0 + t);
    __builtin_nontemporal_store(b, wq1 + t);
  }
}

struct RecT { int dn; int r; float we, wr, ce, cr; };

__device__ __forceinline__ RecT ldrec(int t, int t1,
                                      const unsigned* __restrict__ pk,
                                      const u32x2* __restrict__ wq) {
  bool valid = (t < t1);
  int tc = valid ? t : (t1 - 1);
  unsigned p = pk[tc];
  u32x2 w = wq[tc];
  RecT rec;
  rec.dn = (int)(p & 0xFFFFu);
  rec.r = (int)(p >> 16);
  float2 a = unpack2(w.x);
  float2 b = unpack2(w.y);
  rec.we = valid ? a.x : 0.f;
  rec.wr = valid ? a.y : 0.f;
  rec.ce = valid ? b.x : 0.f;
  rec.cr = valid ? b.y : 0.f;
  return rec;
}

// ---------- one attention layer, both branches fused; 8 triples/iter
// (two independent 4-triple groups, no feature-register rotation) ----------
__global__ __launch_bounds__(256) void attn_kernel(
    float* __restrict__ out, const int* __restrict__ rp,
    const unsigned* __restrict__ pk, const u32x2* __restrict__ wq,
    const __half* __restrict__ relh, const __half* __restrict__ chin,
    __half* __restrict__ chout, int layer) {
  int wid = (blockIdx.x * blockDim.x + threadIdx.x) >> 6;
  int lane = threadIdx.x & 63;
  if (wid >= NN) return;
  int g = lane >> 4;   // triple slot 0..3 within group
  int sl = lane & 15;  // dims [sl*8, sl*8+8)
  int t0 = rp[wid], t1 = rp[wid + 1];

  const u32x4* relh4 = (const u32x4*)relh;
  RecT A = ldrec(t0 + g, t1, pk, wq);
  RecT B = ldrec(t0 + 4 + g, t1, pk, wq);
  float aE[8], aR[8];
#pragma unroll
  for (int i = 0; i < 8; ++i) { aE[i] = 0.f; aR[i] = 0.f; }

  for (int tb = t0; tb < t1; tb += 8) {
    U4H8 uhA, ehA, qhA, uhB, ehB, qhB;
    uhA.u = relh4[(size_t)A.r * 16 + sl];
    const u32x4* phA = (const u32x4*)chin + (size_t)A.dn * 32;
    ehA.u = phA[sl];
    qhA.u = phA[16 + sl];
    uhB.u = relh4[(size_t)B.r * 16 + sl];
    const u32x4* phB = (const u32x4*)chin + (size_t)B.dn * 32;
    ehB.u = phB[sl];
    qhB.u = phB[16 + sl];
    RecT An = ldrec(tb + 8 + g, t1, pk, wq);
    RecT Bn = ldrec(tb + 12 + g, t1, pk, wq);

    float deA = 0.f, drA = 0.f, deB = 0.f, drB = 0.f;
#if __has_builtin(__builtin_amdgcn_fdot2)
#pragma unroll
    for (int i = 0; i < 4; ++i) {
      h16x2 uA = {uhA.h[2 * i], uhA.h[2 * i + 1]};
      h16x2 eA = {ehA.h[2 * i], ehA.h[2 * i + 1]};
      h16x2 qA = {qhA.h[2 * i], qhA.h[2 * i + 1]};
      h16x2 uB = {uhB.h[2 * i], uhB.h[2 * i + 1]};
      h16x2 eB = {ehB.h[2 * i], ehB.h[2 * i + 1]};
      h16x2 qB = {qhB.h[2 * i], qhB.h[2 * i + 1]};
      deA = __builtin_amdgcn_fdot2(uA, eA, deA, false);
      drA = __builtin_amdgcn_fdot2(uA, qA, drA, false);
      deB = __builtin_amdgcn_fdot2(uB, eB, deB, false);
      drB = __builtin_amdgcn_fdot2(uB, qB, drB, false);
    }
#else
#pragma unroll
    for (int i = 0; i < 8; ++i) {
      deA += (float)uhA.h[i] * (float)ehA.h[i];
      drA += (float)uhA.h[i] * (float)qhA.h[i];
      deB += (float)uhB.h[i] * (float)ehB.h[i];
      drB += (float)uhB.h[i] * (float)qhB.h[i];
    }
#endif
#pragma unroll
    for (int off = 1; off < 16; off <<= 1) {
      deA += __shfl_xor(deA, off, 64);
      drA += __shfl_xor(drA, off, 64);
      deB += __shfl_xor(deB, off, 64);
      drB += __shfl_xor(drB, off, 64);
    }
    float ceA = A.ce * deA;  // ce = -2*we/||e_r||^2
    float crA = A.cr * drA;
    float ceB = B.ce * deB;
    float crB = B.cr * drB;
#pragma unroll
    for (int i = 0; i < 8; ++i) {
      float ufA = (float)uhA.h[i];
      float ufB = (float)uhB.h[i];
      aE[i] += A.we * (float)ehA.h[i] + ceA * ufA;
      aE[i] += B.we * (float)ehB.h[i] + ceB * ufB;
      aR[i] += A.wr * (float)qhA.h[i] + crA * ufA;
      aR[i] += B.wr * (float)qhB.h[i] + crB * ufB;
    }
    A = An;
    B = Bn;
  }

#pragma unroll
  for (int i = 0; i < 8; ++i) {
    aE[i] += __shfl_xor(aE[i], 16, 64);
    aE[i] += __shfl_xor(aE[i], 32, 64);
    aR[i] += __shfl_xor(aR[i], 16, 64);
    aR[i] += __shfl_xor(aR[i], 32, 64);
  }

  float4 v;
  if (g == 0) v = make_float4(aE[0], aE[1], aE[2], aE[3]);
  else if (g == 1) v = make_float4(aE[4], aE[5], aE[6], aE[7]);
  else if (g == 2) v = make_float4(aR[0], aR[1], aR[2], aR[3]);
  else v = make_float4(aR[4], aR[5], aR[6], aR[7]);
  v.x = tanhf(v.x); v.y = tanhf(v.y); v.z = tanhf(v.z); v.w = tanhf(v.w);
  float* ob = (g < 2) ? (out + (size_t)wid * OSTRIDE + (layer + 1) * HID)
                      : (out + (size_t)wid * OSTRIDE + (4 + layer) * HID);
  nt_store4(v, ob + sl * 8 + (g & 1) * 4);
  if (chout) {
    u32x2 w; w.x = pack2(v.x, v.y); w.y = pack2(v.z, v.w);
    __builtin_nontemporal_store(
        w, (u32x2*)(chout + (size_t)wid * CH + (g >> 1) * 128 + sl * 8 + (g & 1) * 4));
  }
}

extern "C" void kernel_launch(void* const* d_in, const int* in_sizes, int n_in,
                              void* d_out, int out_size, void* d_ws, size_t ws_size,
                              hipStream_t stream) {
  const float* ent_emb = (const float*)d_in[0];
  const float* rel_emb = (const float*)d_in[1];
  const float* attn_e = (const float*)d_in[2];
  const float* attn_r = (const float*)d_in[3];
  const int* adj = (const int*)d_in[4];
  const int* r_index = (const int*)d_in[5];
  const float* r_val = (const float*)d_in[6];
  const int* ent_adj = (const int*)d_in[7];
  const int* rel_adj = (const int*)d_in[8];
  float* out = (float*)d_out;

  char* ws = (char*)d_ws;
  __half* enth = (__half*)ws;  ws += (size_t)NN * HID * sizeof(__half);  // 12.8 MB
  __half* relh = (__half*)ws;  ws += (size_t)NR * HID * sizeof(__half);  // 0.5 MB
  __half* C0h = (__half*)ws;   ws += (size_t)NN * CH * sizeof(__half);   // 25.6 MB
  __half* C1h = (__half*)ws;   ws += (size_t)NN * CH * sizeof(__half);   // 25.6 MB
  unsigned* pk = (unsigned*)ws; ws += (size_t)NT * sizeof(unsigned);     // 4 MB
  u32x2* wq0 = (u32x2*)ws;     ws += (size_t)NT * sizeof(u32x2);         // 8 MB
  u32x2* wq1 = (u32x2*)ws;     ws += (size_t)NT * sizeof(u32x2);         // 8 MB
  float4* e4 = (float4*)ws;    ws += (size_t)NR * sizeof(float4);
  float* n2i = (float*)ws;     ws += (size_t)NR * sizeof(float);
  int* rp_adj = (int*)ws;      ws += (NN + 1) * sizeof(int);
  int* rp_ent = (int*)ws;      ws += (NN + 1) * sizeof(int);
  int* rp_rel = (int*)ws;      ws += (NN + 1) * sizeof(int);

  dim3 rg(512, 3);
  rowptr3_kernel<<<rg, 256, 0, stream>>>(adj, rp_adj, ent_adj, rp_ent, rel_adj, rp_rel);
  // prep: NR relpre-waves + 13000 cvt-waves = 15000 waves = 3750 blocks
  prep_kernel<<<3750, 256, 0, stream>>>(rel_emb, attn_e, attn_r, e4, n2i,
                                        ent_emb, enth, relh);
  // fused avg (NN waves) + wpre (NN/4 waves) = 62500 waves = 15625 blocks
  avgwpre_kernel<<<15625, 256, 0, stream>>>(
      rp_ent, ent_adj + NT, rp_rel, rel_adj + NT, enth, relh, out, C0h,
      rp_adj, adj + NT, r_index + NT, r_val, e4, n2i, pk, wq0, wq1);
  for (int l = 0; l < 2; ++l) {
    attn_kernel<<<(NN * 64) / 256, 256, 0, stream>>>(
        out, rp_adj, pk, (l == 0) ? wq0 : wq1, relh,
        (l == 0) ? C0h : C1h, (l == 0) ? C1h : nullptr, l);
  }
}

// Round 11
// 439.512 us; speedup vs baseline: 1.1081x; 1.0642x over previous
//
#include <hip/hip_runtime.h>
#include <hip/hip_fp16.h>
#include <math.h>

#define NN 50000
#define NR 2000
#define NT 1000000
#define HID 128
#define OSTRIDE 768
#define CH 256  // halves per compact feature row (e:0..127, r:128..255)

// prep kernel wave-role layout
#define PREP_CVT_W (NR + 1)
#define PREP_CVT_NW 13000
#define PREP_RP_W (PREP_CVT_W + PREP_CVT_NW)
#define PREP_RP_NW 46875  // 3*NT/64
#define PREP_TOT_W (PREP_RP_W + PREP_RP_NW)

typedef float f32x4 __attribute__((ext_vector_type(4)));
typedef unsigned u32x4 __attribute__((ext_vector_type(4)));
typedef unsigned u32x2 __attribute__((ext_vector_type(2)));
typedef _Float16 h16x2 __attribute__((ext_vector_type(2)));
typedef _Float16 h16x8 __attribute__((ext_vector_type(8)));

union U4H8 { u32x4 u; h16x8 h; };

__device__ __forceinline__ float wsum64(float v) {
#pragma unroll
  for (int off = 32; off > 0; off >>= 1) v += __shfl_xor(v, off, 64);
  return v;
}
__device__ __forceinline__ unsigned pack2(float x, float y) {
  __half2 h = __floats2half2_rn(x, y);
  union { __half2 h; unsigned u; } c; c.h = h; return c.u;
}
__device__ __forceinline__ float2 unpack2(unsigned u) {
  union { unsigned u; __half2 h; } c; c.u = u;
  return __half22float2(c.h);
}
__device__ __forceinline__ void nt_store4(const float4& v, float* p) {
  f32x4 t = {v.x, v.y, v.z, v.w};
  __builtin_nontemporal_store(t, (f32x4*)p);
}

// ---------- prep: per-relation tables + normalized-u table + fp16 mirrors
//            + row pointers for all three adjacencies (fused roles) ----------
__global__ __launch_bounds__(256) void prep_kernel(
    const float* __restrict__ rel_emb, const float* __restrict__ attn_e,
    const float* __restrict__ attn_r, const float* __restrict__ ent_emb,
    float4* __restrict__ e4, __half* __restrict__ enth,
    __half* __restrict__ relh, __half* __restrict__ relnh,
    const int* __restrict__ rows_adj, const int* __restrict__ rows_ent,
    const int* __restrict__ rows_rel, int* __restrict__ rp_adj,
    int* __restrict__ rp_ent, int* __restrict__ rp_rel) {
  int wid = (blockIdx.x * blockDim.x + threadIdx.x) >> 6;
  int lane = threadIdx.x & 63;

  if (wid < NR) {  // ---- relpre role ----
    const float2* e2 = (const float2*)rel_emb;
    float2 e = e2[(size_t)wid * 64 + lane];
    float p = wsum64(e.x * e.x + e.y * e.y);  // norm^2
    float inv_n = rsqrtf(p);
    // normalized fp16 row (this IS the reference's tri_rel for rv>0)
    ((unsigned*)relnh)[(size_t)wid * 64 + lane] = pack2(e.x * inv_n, e.y * inv_n);
    const float* ks[4] = {attn_e, attn_e + HID, attn_r, attn_r + HID};
    float d[4];
#pragma unroll
    for (int j = 0; j < 4; ++j) {
      float2 a = ((const float2*)ks[j])[lane];
      d[j] = wsum64(e.x * a.x + e.y * a.y);
    }
    if (lane == 0) {
      e4[wid] = make_float4(expf(d[0] * inv_n), expf(d[1] * inv_n),
                            expf(d[2] * inv_n), expf(d[3] * inv_n));
    }
    return;
  }
  if (wid == NR) {  // ---- zero-row + rp-end role ----
    ((unsigned*)relnh)[(size_t)NR * 64 + lane] = 0u;
    if (lane == 0) { rp_adj[NN] = NT; rp_ent[NN] = NT; rp_rel[NN] = NT; }
    return;
  }
  if (wid < PREP_RP_W) {  // ---- cvt role: unit i covers 8 f32 ----
    int i = (wid - PREP_CVT_W) * 64 + lane;
    const int entu = NN * 16;
    const float4* s4;
    u32x4* d;
    int j;
    if (i < entu) {
      s4 = (const float4*)ent_emb; d = (u32x4*)enth; j = i;
    } else {
      j = i - entu;
      if (j >= NR * 16) return;
      s4 = (const float4*)rel_emb; d = (u32x4*)relh;
    }
    float4 a = s4[2 * j], b = s4[2 * j + 1];
    u32x4 w;
    w.x = pack2(a.x, a.y); w.y = pack2(a.z, a.w);
    w.z = pack2(b.x, b.y); w.w = pack2(b.z, b.w);
    __builtin_nontemporal_store(w, d + j);
    return;
  }
  if (wid >= PREP_TOT_W) return;
  // ---- rowptr role: one element per lane, 3*NT total ----
  int idx = (wid - PREP_RP_W) * 64 + lane;
  int arr = idx / NT;
  int t = idx - arr * NT;
  const int* rows = (arr == 0) ? rows_adj : (arr == 1) ? rows_ent : rows_rel;
  int* rp = (arr == 0) ? rp_adj : (arr == 1) ? rp_ent : rp_rel;
  int rcur = rows[t];
  if (t == 0 || rows[t - 1] != rcur) rp[rcur] = t;
}

// ---------- fused: layer-0 segment mean+tanh (waves 0..NN-1, 8 rows/iter)
//            + per-triple record precompute (next NN/4 waves, 16 lanes/node) ----------
__global__ __launch_bounds__(256) void avgwpre_kernel(
    const int* __restrict__ rp_ent, const int* __restrict__ cols_ent,
    const int* __restrict__ rp_rel, const int* __restrict__ cols_rel,
    const __half* __restrict__ enth, const __half* __restrict__ relh,
    float* __restrict__ out, __half* __restrict__ c0h,
    const int* __restrict__ rp_adj, const int* __restrict__ dst,
    const int* __restrict__ rel_id, const float* __restrict__ r_val,
    const float4* __restrict__ e4, unsigned* __restrict__ pk,
    unsigned* __restrict__ wq0, unsigned* __restrict__ wq1) {
  int wid = (blockIdx.x * blockDim.x + threadIdx.x) >> 6;
  int lane = threadIdx.x & 63;

  if (wid < NN) {  // ---- avg role: 2 nodes/wave, 8 rows in flight per node ----
    int br = (wid >= NN / 2) ? 1 : 0;
    int pair = wid - br * (NN / 2);
    int node = pair * 2 + (lane >> 5);
    int sl = lane & 31;
    const int* rp = br ? rp_rel : rp_ent;
    const int* cols = br ? cols_rel : cols_ent;
    const u32x2* eb = (const u32x2*)(br ? relh : enth);
    int t0 = rp[node], t1 = rp[node + 1];
    int nmax = t1 - 1;
    int i0 = cols[t0];
    int i1 = cols[min(t0 + 1, nmax)];
    int i2 = cols[min(t0 + 2, nmax)];
    int i3 = cols[min(t0 + 3, nmax)];
    int i4 = cols[min(t0 + 4, nmax)];
    int i5 = cols[min(t0 + 5, nmax)];
    int i6 = cols[min(t0 + 6, nmax)];
    int i7 = cols[min(t0 + 7, nmax)];
    float4 acc = make_float4(0.f, 0.f, 0.f, 0.f);
    const u32x2 z = {0u, 0u};
    for (int t = t0; t < t1; t += 8) {
      u32x2 h0 = eb[(size_t)i0 * 32 + sl];
      u32x2 h1 = eb[(size_t)i1 * 32 + sl];
      u32x2 h2 = eb[(size_t)i2 * 32 + sl];
      u32x2 h3 = eb[(size_t)i3 * 32 + sl];
      u32x2 h4 = eb[(size_t)i4 * 32 + sl];
      u32x2 h5 = eb[(size_t)i5 * 32 + sl];
      u32x2 h6 = eb[(size_t)i6 * 32 + sl];
      u32x2 h7 = eb[(size_t)i7 * 32 + sl];
      int tn = t + 8;
      i0 = cols[min(tn, nmax)];
      i1 = cols[min(tn + 1, nmax)];
      i2 = cols[min(tn + 2, nmax)];
      i3 = cols[min(tn + 3, nmax)];
      i4 = cols[min(tn + 4, nmax)];
      i5 = cols[min(tn + 5, nmax)];
      i6 = cols[min(tn + 6, nmax)];
      i7 = cols[min(tn + 7, nmax)];
      h1 = (t + 1 < t1) ? h1 : z;
      h2 = (t + 2 < t1) ? h2 : z;
      h3 = (t + 3 < t1) ? h3 : z;
      h4 = (t + 4 < t1) ? h4 : z;
      h5 = (t + 5 < t1) ? h5 : z;
      h6 = (t + 6 < t1) ? h6 : z;
      h7 = (t + 7 < t1) ? h7 : z;
      float2 a0 = unpack2(h0.x), b0 = unpack2(h0.y);
      float2 a1 = unpack2(h1.x), b1 = unpack2(h1.y);
      float2 a2 = unpack2(h2.x), b2 = unpack2(h2.y);
      float2 a3 = unpack2(h3.x), b3 = unpack2(h3.y);
      float2 a4 = unpack2(h4.x), b4 = unpack2(h4.y);
      float2 a5 = unpack2(h5.x), b5 = unpack2(h5.y);
      float2 a6 = unpack2(h6.x), b6 = unpack2(h6.y);
      float2 a7 = unpack2(h7.x), b7 = unpack2(h7.y);
      acc.x += ((a0.x + a1.x) + (a2.x + a3.x)) + ((a4.x + a5.x) + (a6.x + a7.x));
      acc.y += ((a0.y + a1.y) + (a2.y + a3.y)) + ((a4.y + a5.y) + (a6.y + a7.y));
      acc.z += ((b0.x + b1.x) + (b2.x + b3.x)) + ((b4.x + b5.x) + (b6.x + b7.x));
      acc.w += ((b0.y + b1.y) + (b2.y + b3.y)) + ((b4.y + b5.y) + (b6.y + b7.y));
    }
    float inv = 1.f / (float)(t1 - t0);
    float4 o;
    o.x = tanhf(acc.x * inv); o.y = tanhf(acc.y * inv);
    o.z = tanhf(acc.z * inv); o.w = tanhf(acc.w * inv);
    nt_store4(o, out + (size_t)node * OSTRIDE + (br ? 3 * HID : 0) + sl * 4);
    u32x2 w; w.x = pack2(o.x, o.y); w.y = pack2(o.z, o.w);
    __builtin_nontemporal_store(w,
        (u32x2*)(c0h + (size_t)node * CH + br * HID + sl * 4));
    return;
  }

  wid -= NN;
  if (wid >= NN / 4) return;
  // ---- wpre role: 4 nodes/wave, 16 lanes per node ----
  int sub = lane >> 4;
  int s = lane & 15;
  int node = wid * 4 + sub;
  int t0 = rp_adj[node], t1 = rp_adj[node + 1];
  float4 ss = make_float4(0.f, 0.f, 0.f, 0.f);
  for (int t = t0 + s; t < t1; t += 16) {
    int r = rel_id[t];
    float rv = r_val[t];
    float4 ex = e4[r];
    if (rv <= 0.f) ex = make_float4(1.f, 1.f, 1.f, 1.f);
    ss.x += ex.x; ss.y += ex.y; ss.z += ex.z; ss.w += ex.w;
  }
#pragma unroll
  for (int off = 1; off < 16; off <<= 1) {
    ss.x += __shfl_xor(ss.x, off, 64);
    ss.y += __shfl_xor(ss.y, off, 64);
    ss.z += __shfl_xor(ss.z, off, 64);
    ss.w += __shfl_xor(ss.w, off, 64);
  }
  float4 inv = make_float4(1.f / ss.x, 1.f / ss.y, 1.f / ss.z, 1.f / ss.w);
  for (int t = t0 + s; t < t1; t += 16) {
    int r = rel_id[t];
    float rv = r_val[t];
    int dn = dst[t];
    float4 ex = e4[r];
    int ru = r;
    if (rv <= 0.f) {  // zero-scale triple: exp(0)=1 weights, zero u-row
      ex = make_float4(1.f, 1.f, 1.f, 1.f);
      ru = NR;
    }
    float we0 = ex.x * inv.x, wr0 = ex.z * inv.z;
    float we1 = ex.y * inv.y, wr1 = ex.w * inv.w;
    __builtin_nontemporal_store((unsigned)dn | ((unsigned)ru << 16), pk + t);
    __builtin_nontemporal_store(pack2(we0, wr0), wq0 + t);
    __builtin_nontemporal_store(pack2(we1, wr1), wq1 + t);
  }
}

struct RecT { int dn; int r; float we, wr; };

__device__ __forceinline__ RecT ldrec(int t, int t1,
                                      const unsigned* __restrict__ pk,
                                      const unsigned* __restrict__ wq) {
  bool valid = (t < t1);
  int tc = valid ? t : (t1 - 1);
  unsigned p = pk[tc];
  float2 a = unpack2(wq[tc]);
  RecT rec;
  rec.dn = (int)(p & 0xFFFFu);
  rec.r = (int)(p >> 16);
  rec.we = valid ? a.x : 0.f;
  rec.wr = valid ? a.y : 0.f;
  return rec;
}

// ---------- one attention layer, both branches fused; 4 triples/iter;
// fp16 gathers with normalized-u table; record prefetch (r7 structure) ----------
__global__ __launch_bounds__(256) void attn_kernel(
    float* __restrict__ out, const int* __restrict__ rp,
    const unsigned* __restrict__ pk, const unsigned* __restrict__ wq,
    const __half* __restrict__ relnh, const __half* __restrict__ chin,
    __half* __restrict__ chout, int layer) {
  int wid = (blockIdx.x * blockDim.x + threadIdx.x) >> 6;
  int lane = threadIdx.x & 63;
  if (wid >= NN) return;
  int g = lane >> 4;   // triple slot 0..3
  int sl = lane & 15;  // dims [sl*8, sl*8+8)
  int t0 = rp[wid], t1 = rp[wid + 1];

  const u32x4* relnh4 = (const u32x4*)relnh;
  RecT b0 = ldrec(t0 + g, t1, pk, wq);
  float aE[8], aR[8];
#pragma unroll
  for (int i = 0; i < 8; ++i) { aE[i] = 0.f; aR[i] = 0.f; }

  for (int tb = t0; tb < t1; tb += 4) {
    U4H8 uh, eh, qh;
    uh.u = relnh4[(size_t)b0.r * 16 + sl];
    const u32x4* ph = (const u32x4*)chin + (size_t)b0.dn * 32;
    eh.u = ph[sl];
    qh.u = ph[16 + sl];
    RecT b1 = ldrec(tb + 4 + g, t1, pk, wq);

    float de = 0.f, dr = 0.f;
#if __has_builtin(__builtin_amdgcn_fdot2)
#pragma unroll
    for (int i = 0; i < 4; ++i) {
      h16x2 up = {uh.h[2 * i], uh.h[2 * i + 1]};
      h16x2 ep = {eh.h[2 * i], eh.h[2 * i + 1]};
      h16x2 qp = {qh.h[2 * i], qh.h[2 * i + 1]};
      de = __builtin_amdgcn_fdot2(up, ep, de, false);
      dr = __builtin_amdgcn_fdot2(up, qp, dr, false);
    }
#else
#pragma unroll
    for (int i = 0; i < 8; ++i) {
      de += (float)uh.h[i] * (float)eh.h[i];
      dr += (float)uh.h[i] * (float)qh.h[i];
    }
#endif
#pragma unroll
    for (int off = 1; off < 16; off <<= 1) {
      de += __shfl_xor(de, off, 64);
      dr += __shfl_xor(dr, off, 64);
    }
    float ce = -2.f * b0.we * de;  // u is unit-norm: reflection = nb - 2(nb.u)u
    float cr = -2.f * b0.wr * dr;
#pragma unroll
    for (int i = 0; i < 8; ++i) {
      float uf = (float)uh.h[i];
      aE[i] += b0.we * (float)eh.h[i] + ce * uf;
      aR[i] += b0.wr * (float)qh.h[i] + cr * uf;
    }
    b0 = b1;
  }

#pragma unroll
  for (int i = 0; i < 8; ++i) {
    aE[i] += __shfl_xor(aE[i], 16, 64);
    aE[i] += __shfl_xor(aE[i], 32, 64);
    aR[i] += __shfl_xor(aR[i], 16, 64);
    aR[i] += __shfl_xor(aR[i], 32, 64);
  }

  float4 v;
  if (g == 0) v = make_float4(aE[0], aE[1], aE[2], aE[3]);
  else if (g == 1) v = make_float4(aE[4], aE[5], aE[6], aE[7]);
  else if (g == 2) v = make_float4(aR[0], aR[1], aR[2], aR[3]);
  else v = make_float4(aR[4], aR[5], aR[6], aR[7]);
  v.x = tanhf(v.x); v.y = tanhf(v.y); v.z = tanhf(v.z); v.w = tanhf(v.w);
  float* ob = (g < 2) ? (out + (size_t)wid * OSTRIDE + (layer + 1) * HID)
                      : (out + (size_t)wid * OSTRIDE + (4 + layer) * HID);
  nt_store4(v, ob + sl * 8 + (g & 1) * 4);
  if (chout) {
    u32x2 w; w.x = pack2(v.x, v.y); w.y = pack2(v.z, v.w);
    __builtin_nontemporal_store(
        w, (u32x2*)(chout + (size_t)wid * CH + (g >> 1) * 128 + sl * 8 + (g & 1) * 4));
  }
}

extern "C" void kernel_launch(void* const* d_in, const int* in_sizes, int n_in,
                              void* d_out, int out_size, void* d_ws, size_t ws_size,
                              hipStream_t stream) {
  const float* ent_emb = (const float*)d_in[0];
  const float* rel_emb = (const float*)d_in[1];
  const float* attn_e = (const float*)d_in[2];
  const float* attn_r = (const float*)d_in[3];
  const int* adj = (const int*)d_in[4];
  const int* r_index = (const int*)d_in[5];
  const float* r_val = (const float*)d_in[6];
  const int* ent_adj = (const int*)d_in[7];
  const int* rel_adj = (const int*)d_in[8];
  float* out = (float*)d_out;

  char* ws = (char*)d_ws;
  __half* enth = (__half*)ws;   ws += (size_t)NN * HID * sizeof(__half);       // 12.8 MB
  __half* relh = (__half*)ws;   ws += (size_t)NR * HID * sizeof(__half);       // 0.5 MB
  __half* relnh = (__half*)ws;  ws += (size_t)(NR + 1) * HID * sizeof(__half); // 0.5 MB
  __half* C0h = (__half*)ws;    ws += (size_t)NN * CH * sizeof(__half);        // 25.6 MB
  __half* C1h = (__half*)ws;    ws += (size_t)NN * CH * sizeof(__half);        // 25.6 MB
  unsigned* pk = (unsigned*)ws;  ws += (size_t)NT * sizeof(unsigned);          // 4 MB
  unsigned* wq0 = (unsigned*)ws; ws += (size_t)NT * sizeof(unsigned);          // 4 MB
  unsigned* wq1 = (unsigned*)ws; ws += (size_t)NT * sizeof(unsigned);          // 4 MB
  float4* e4 = (float4*)ws;     ws += (size_t)NR * sizeof(float4);
  int* rp_adj = (int*)ws;       ws += (NN + 1) * sizeof(int);
  int* rp_ent = (int*)ws;       ws += (NN + 1) * sizeof(int);
  int* rp_rel = (int*)ws;       ws += (NN + 1) * sizeof(int);

  // prep (all roles fused): (PREP_TOT_W waves + pad) / 4 waves per block
  prep_kernel<<<(PREP_TOT_W + 3) / 4, 256, 0, stream>>>(
      rel_emb, attn_e, attn_r, ent_emb, e4, enth, relh, relnh,
      adj, ent_adj, rel_adj, rp_adj, rp_ent, rp_rel);
  // fused avg (NN waves) + wpre (NN/4 waves) = 62500 waves = 15625 blocks
  avgwpre_kernel<<<15625, 256, 0, stream>>>(
      rp_ent, ent_adj + NT, rp_rel, rel_adj + NT, enth, relh, out, C0h,
      rp_adj, adj + NT, r_index + NT, r_val, e4, pk, wq0, wq1);
  for (int l = 0; l < 2; ++l) {
    attn_kernel<<<(NN * 64) / 256, 256, 0, stream>>>(
        out, rp_adj, pk, (l == 0) ? wq0 : wq1, relnh,
        (l == 0) ? C0h : C1h, (l == 0) ? C1h : nullptr, l);
  }
}